// Round 2
// baseline (708.466 us; speedup 1.0000x reference)
//
#include <hip/hip_runtime.h>
#include <stdint.h>

// Sampler: temperature=1.0, top_p=0.9, top_k=50, neg-entropy confidence.
// logits [1024, 128000] fp32. Outputs (float): confidence[1024], x0[1024], initial_confidence[1024].
//
// One block per row; single streamed pass computes online (max, sum-exp) and
// collects candidates >= T0 into LDS; top-50 by repeated wave-argmax; shifted
// top-p rule on the sorted prefix; entropy/sample over the <=~51 kept tokens.
//
// RNG: JAX >=0.5 defaults jax_threefry_partitionable=True. Partitionable
// scheme: per-element 64-bit flat index (C order) -> counter pair
// (hi=lin>>32 (=0 here), lo=lin), threefry2x32 with key (0,42), 32-bit
// output = out0 ^ out1 (xor-fold of the 64-bit PRF output).
// uniform = (bits>>9 | 0x3F800000) - 1.0f (+tiny), gumbel = -log(-log(u)).

#define ROWS   1024
#define VOCAB  128000
#define CAP    2048
#define KTOP   50
#define TOPP   0.9f
#define NTHR   256

__device__ __forceinline__ void tf_round(uint32_t& x0, uint32_t& x1, int r) {
  x0 += x1;
  x1 = (x1 << r) | (x1 >> (32 - r));
  x1 ^= x0;
}

// JAX threefry2x32, key = (0, 42), partitionable bits: counter = (0, lin),
// output = x0 ^ x1.
__device__ __forceinline__ uint32_t threefry_bits(uint32_t lin) {
  const uint32_t ks0 = 0u;
  const uint32_t ks1 = 42u;
  const uint32_t ks2 = 0x1BD11BDAu ^ 0u ^ 42u;
  uint32_t x0 = 0u + ks0, x1 = lin + ks1;
  tf_round(x0,x1,13); tf_round(x0,x1,15); tf_round(x0,x1,26); tf_round(x0,x1,6);
  x0 += ks1; x1 += ks2 + 1u;
  tf_round(x0,x1,17); tf_round(x0,x1,29); tf_round(x0,x1,16); tf_round(x0,x1,24);
  x0 += ks2; x1 += ks0 + 2u;
  tf_round(x0,x1,13); tf_round(x0,x1,15); tf_round(x0,x1,26); tf_round(x0,x1,6);
  x0 += ks0; x1 += ks1 + 3u;
  tf_round(x0,x1,17); tf_round(x0,x1,29); tf_round(x0,x1,16); tf_round(x0,x1,24);
  x0 += ks1; x1 += ks2 + 4u;
  tf_round(x0,x1,13); tf_round(x0,x1,15); tf_round(x0,x1,26); tf_round(x0,x1,6);
  x0 += ks2; x1 += ks0 + 5u;
  return x0 ^ x1;
}

__device__ __forceinline__ float gumbel_at(uint32_t lin) {
  uint32_t bits = threefry_bits(lin);
  float f = __uint_as_float((bits >> 9) | 0x3F800000u) - 1.0f;  // [0,1)
  float u = f + 1.17549435e-38f;   // JAX: floats*(1-tiny)+tiny folds to f+tiny in fp32
  return -logf(-logf(u));
}

__global__ __launch_bounds__(NTHR) void sampler_kernel(
    const float* __restrict__ logits, float* __restrict__ out) {
  const int row = blockIdx.x;
  const int tid = threadIdx.x;
  const float* __restrict__ rowp = logits + (size_t)row * VOCAB;

  __shared__ float cand_val[CAP];
  __shared__ int   cand_idx[CAP];
  __shared__ float red_a[NTHR];
  __shared__ float red_b[NTHR];
  __shared__ int   red_i[NTHR];
  __shared__ int   red_i2[NTHR];
  __shared__ int   s_cnt;
  __shared__ float s_topv[KTOP];
  __shared__ int   s_tops[KTOP];
  __shared__ float s_kth;

  if (tid == 0) s_cnt = 0;
  __syncthreads();

  const float T0 = 6.0f;   // expected ~170 candidates/row; row z_(50) ~ 6.7
  float m_loc = -__builtin_inff();
  float s_loc = 0.0f;

  const float4* __restrict__ rowp4 = reinterpret_cast<const float4*>(rowp);
  // 32000 float4 per row; process two per thread-iteration for load ILP.
  for (int i2 = tid; i2 < (VOCAB/8); i2 += NTHR) {
    const int ia = 2*i2, ib = 2*i2 + 1;
    float4 a = rowp4[ia];
    float4 b = rowp4[ib];
    float xs[8] = {a.x, a.y, a.z, a.w, b.x, b.y, b.z, b.w};
#pragma unroll
    for (int j = 0; j < 8; ++j) {
      float x = xs[j];
      if (x <= m_loc) {
        s_loc += __expf(x - m_loc);
      } else {
        s_loc = s_loc * __expf(m_loc - x) + 1.0f;
        m_loc = x;
      }
      if (x >= T0) {
        int slot = atomicAdd(&s_cnt, 1);
        if (slot < CAP) { cand_val[slot] = x; cand_idx[slot] = 4*ia + j; }
      }
    }
  }

  // Block-reduce (m, s) online-softmax pairs.
  red_a[tid] = m_loc; red_b[tid] = s_loc;
  __syncthreads();
  for (int off = NTHR/2; off > 0; off >>= 1) {
    if (tid < off) {
      float m1 = red_a[tid],     s1 = red_b[tid];
      float m2 = red_a[tid+off], s2 = red_b[tid+off];
      float mm = fmaxf(m1, m2);
      float ss = 0.0f;
      if (mm > -__builtin_inff())
        ss = s1 * __expf(m1 - mm) + s2 * __expf(m2 - mm);
      red_a[tid] = mm; red_b[tid] = ss;
    }
    __syncthreads();
  }
  const float m = red_a[0];   // row max (= top-1 value)
  const float S = red_b[0];   // sum exp(z - m) over full row

  int total = s_cnt;
  // Fallback (never taken for this input distribution): threshold search.
  if (total < KTOP || total > CAP) {
    float delta = 2.0f;
    float Tt = m - delta;
    for (int attempt = 0; attempt < 20; ++attempt) {
      Tt = m - delta;
      int c_loc = 0;
      for (int i = tid; i < VOCAB; i += NTHR) c_loc += (rowp[i] >= Tt) ? 1 : 0;
      red_i[tid] = c_loc;
      __syncthreads();
      for (int off = NTHR/2; off > 0; off >>= 1) {
        if (tid < off) red_i[tid] += red_i[tid+off];
        __syncthreads();
      }
      int tot = red_i[0];
      __syncthreads();
      if (tot >= KTOP && tot <= CAP) break;
      delta = (tot < KTOP) ? delta * 2.0f : delta * 0.7f;
    }
    if (tid == 0) s_cnt = 0;
    __syncthreads();
    for (int i = tid; i < VOCAB; i += NTHR) {
      float x = rowp[i];
      if (x >= Tt) {
        int slot = atomicAdd(&s_cnt, 1);
        if (slot < CAP) { cand_val[slot] = x; cand_idx[slot] = i; }
      }
    }
    __syncthreads();
    total = s_cnt;
  }
  const int cnt = total < CAP ? total : CAP;

  if (cnt == 0) {  // degenerate guard (uniform across block)
    if (tid == 0) { out[row] = 0.f; out[ROWS+row] = 0.f; out[2*ROWS+row] = 0.f; }
    return;
  }

  const int nsel = cnt < KTOP ? cnt : KTOP;

  // Wave 0 extracts top-nsel by repeated argmax; applies shifted top-p rule:
  // sorted token j (j>=1) removed iff cum[j-1] > 0.9  ->  nkeep = first such j.
  if (tid < 64) {
    volatile float* cv = cand_val;
    float cum = 0.0f;
    int nkeep = nsel;
    bool found = false;
    for (int j = 0; j < nsel; ++j) {
      float bv = -__builtin_inff(); int bs = -1;
      for (int c = tid; c < cnt; c += 64) {
        float v = cv[c];
        if (v > bv) { bv = v; bs = c; }
      }
      for (int off = 32; off > 0; off >>= 1) {
        float ov = __shfl_down(bv, off);
        int   os = __shfl_down(bs, off);
        if (ov > bv || (ov == bv && (unsigned)os < (unsigned)bs)) { bv = ov; bs = os; }
      }
      bs = __shfl(bs, 0);
      bv = __shfl(bv, 0);
      if (tid == 0) {
        s_topv[j] = bv; s_tops[j] = bs;
        if (j >= 1 && !found && cum > TOPP) { nkeep = j; found = true; }
        cum += __expf(bv - m) / S;    // full-softmax prob of sorted token j
        cv[bs] = -__builtin_inff();   // remove from further argmax rounds
      }
    }
    if (tid == 0) {
      s_kth = s_topv[nkeep - 1];      // kth-largest kept value
    }
  }
  __syncthreads();

  // Restore extracted candidate values (needed for the kept-set loops).
  for (int j = tid; j < nsel; j += NTHR) cand_val[s_tops[j]] = s_topv[j];
  __syncthreads();

  const float kth = s_kth;

  // S' = sum exp(z - m) over kept tokens (z >= kth).
  float sp_loc = 0.0f;
  for (int c = tid; c < cnt; c += NTHR) {
    float v = cand_val[c];
    if (v >= kth) sp_loc += expf(v - m);
  }
  red_a[tid] = sp_loc;
  __syncthreads();
  for (int off = NTHR/2; off > 0; off >>= 1) {
    if (tid < off) red_a[tid] += red_a[tid+off];
    __syncthreads();
  }
  const float Sp = red_a[0];
  __syncthreads();

  // Neg-entropy + Gumbel argmax over kept tokens.
  float conf_loc = 0.0f;
  float bsc = -__builtin_inff(); int bidx = 0x7FFFFFFF; int bslot = -1;
  const uint32_t rowbase = (uint32_t)row * (uint32_t)VOCAB;
  for (int c = tid; c < cnt; c += NTHR) {
    float v = cand_val[c];
    if (v >= kth) {
      float p = expf(v - m) / Sp;
      conf_loc += p * logf(p + 1e-10f);
      int col = cand_idx[c];
      float sc = v + gumbel_at(rowbase + (uint32_t)col);
      if (sc > bsc || (sc == bsc && col < bidx)) { bsc = sc; bidx = col; bslot = c; }
    }
  }
  red_a[tid] = conf_loc;
  red_b[tid] = bsc; red_i[tid] = bidx; red_i2[tid] = bslot;
  __syncthreads();
  for (int off = NTHR/2; off > 0; off >>= 1) {
    if (tid < off) {
      red_a[tid] += red_a[tid+off];
      float s2 = red_b[tid+off]; int i2 = red_i[tid+off]; int l2 = red_i2[tid+off];
      if (s2 > red_b[tid] || (s2 == red_b[tid] && i2 < red_i[tid])) {
        red_b[tid] = s2; red_i[tid] = i2; red_i2[tid] = l2;
      }
    }
    __syncthreads();
  }
  if (tid == 0) {
    int wslot = red_i2[0];
    float pw = (wslot >= 0) ? expf(cand_val[wslot] - m) / Sp : 0.0f;
    out[row]          = red_a[0];            // confidence (neg entropy)
    out[ROWS + row]   = (float)red_i[0];     // sampled index (exact in fp32)
    out[2*ROWS + row] = pw;                  // initial_confidence
  }
}

extern "C" void kernel_launch(void* const* d_in, const int* in_sizes, int n_in,
                              void* d_out, int out_size, void* d_ws, size_t ws_size,
                              hipStream_t stream) {
  const float* logits = (const float*)d_in[0];
  float* out = (float*)d_out;
  sampler_kernel<<<ROWS, NTHR, 0, stream>>>(logits, out);
}